// Round 1
// baseline (1485.415 us; speedup 1.0000x reference)
//
#include <hip/hip_runtime.h>
#include <hip/hip_bf16.h>

// Problem constants
constexpr int B  = 2;
constexpr int S  = 2048;
constexpr int D  = 1024;
constexpr int H  = 16;
constexpr int Dh = 64;

__device__ __forceinline__ float b2f(unsigned short u) {
    union { unsigned int i; float f; } c; c.i = ((unsigned int)u) << 16; return c.f;
}
__device__ __forceinline__ unsigned short f2b(float f) {
    __hip_bfloat16 h = __float2bfloat16(f);
    union { __hip_bfloat16 h; unsigned short u; } c; c.h = h; return c.u;
}

// ---------------------------------------------------------------------------
// Kernel 1: QKV projection.  q[b,h,s,dh] = sum_d x[b,s,d]*W[e,d] + bias[e]
// fp32 tiled GEMM: BM=64, BN=64, BK=16, 256 threads, 4x4 per thread.
// grid = (M/64=64, N/64=16, 3)  z picks (Wq,bq,q)/(Wk,bk,k)/(Wv,bv,v)
// ---------------------------------------------------------------------------
__global__ __launch_bounds__(256) void qkv_proj(
    const float* __restrict__ x,
    const float* __restrict__ Wq, const float* __restrict__ bq,
    const float* __restrict__ Wk, const float* __restrict__ bk,
    const float* __restrict__ Wv, const float* __restrict__ bv,
    float* __restrict__ qo, float* __restrict__ ko, float* __restrict__ vo)
{
    const int z = blockIdx.z;
    const float* W    = (z == 0) ? Wq : (z == 1) ? Wk : Wv;
    const float* bias = (z == 0) ? bq : (z == 1) ? bk : bv;
    float*       out  = (z == 0) ? qo : (z == 1) ? ko : vo;

    __shared__ float Xs[16][68];  // [k][m]
    __shared__ float Ws[16][68];  // [k][n]

    const int tid = threadIdx.x;
    const int tm = tid & 15;        // m-group
    const int tn = tid >> 4;        // n-group
    const int m0 = blockIdx.x * 64;
    const int n0 = blockIdx.y * 64;

    const int lr = tid >> 2;         // 0..63 (row within tile)
    const int lc = (tid & 3) << 2;   // 0,4,8,12 (k offset)

    float acc[4][4] = {};

    for (int k0 = 0; k0 < D; k0 += 16) {
        float4 xa = *(const float4*)&x[(size_t)(m0 + lr) * D + k0 + lc];
        float4 wa = *(const float4*)&W[(size_t)(n0 + lr) * D + k0 + lc];
        __syncthreads();
        Xs[lc + 0][lr] = xa.x; Xs[lc + 1][lr] = xa.y;
        Xs[lc + 2][lr] = xa.z; Xs[lc + 3][lr] = xa.w;
        Ws[lc + 0][lr] = wa.x; Ws[lc + 1][lr] = wa.y;
        Ws[lc + 2][lr] = wa.z; Ws[lc + 3][lr] = wa.w;
        __syncthreads();
        #pragma unroll
        for (int kk = 0; kk < 16; ++kk) {
            float4 a4 = *(const float4*)&Xs[kk][tm * 4];
            float4 b4 = *(const float4*)&Ws[kk][tn * 4];
            float av[4] = { a4.x, a4.y, a4.z, a4.w };
            float bw[4] = { b4.x, b4.y, b4.z, b4.w };
            #pragma unroll
            for (int i = 0; i < 4; ++i)
                #pragma unroll
                for (int j = 0; j < 4; ++j)
                    acc[i][j] += av[i] * bw[j];
        }
    }

    // n0 is a multiple of 64, so the whole block is one head.
    const int h = n0 >> 6;
    float4 bias4 = *(const float4*)&bias[n0 + tn * 4];
    float bb[4] = { bias4.x, bias4.y, bias4.z, bias4.w };
    #pragma unroll
    for (int i = 0; i < 4; ++i) {
        int m = m0 + tm * 4 + i;
        int b_ = m >> 11;          // S = 2048
        int s  = m & (S - 1);
        float4 o;
        o.x = acc[i][0] + bb[0];
        o.y = acc[i][1] + bb[1];
        o.z = acc[i][2] + bb[2];
        o.w = acc[i][3] + bb[3];
        *(float4*)&out[(((size_t)(b_ * H + h)) * S + s) * Dh + tn * 4] = o;
    }
}

// ---------------------------------------------------------------------------
// Kernel 2: flash attention with relative-position term.
// score(s,t) = ( q_s·k_t + q_s·Er[S-1-s+t] ) / 8,  causal.
// One block per (bh, 64-row q tile). BN=64 t-tiles, online softmax.
// LDS staged in bf16 (59.7 KB total), fp32 accumulate.
// ---------------------------------------------------------------------------
__global__ __launch_bounds__(256) void attn_kernel(
    const float* __restrict__ q, const float* __restrict__ k,
    const float* __restrict__ v, const float* __restrict__ Er,
    float* __restrict__ out)
{
    __shared__ unsigned short Qs [64][68];   // [d][m]
    __shared__ unsigned short KsT[64][68];   // [d][n]
    __shared__ unsigned short Vs [64][68];   // [n][dh]
    __shared__ unsigned short Es [64][132];  // [d][z], z in [0,128)
    __shared__ float Sc[64][68];             // [n][m]
    __shared__ float rowm[64], rowl[64], rowA[64];

    const int tid = threadIdx.x;
    const int ix  = blockIdx.x;       // q tile index
    const int bh  = blockIdx.y;       // b*H + h
    const int s0  = ix * 64;
    const int hh  = bh & (H - 1);
    const int bb  = bh >> 4;

    const float* qb = q + (size_t)bh * S * Dh;
    const float* kb = k + (size_t)bh * S * Dh;
    const float* vb = v + (size_t)bh * S * Dh;

    // Stage Q tile (transposed to [d][m]) as bf16
    #pragma unroll
    for (int it = 0; it < 4; ++it) {
        int idx = tid + it * 256;       // 0..1023
        int r  = idx >> 4;              // row 0..63
        int c4 = idx & 15;              // float4 within row
        float4 val = *(const float4*)&qb[(size_t)(s0 + r) * Dh + c4 * 4];
        Qs[c4 * 4 + 0][r] = f2b(val.x);
        Qs[c4 * 4 + 1][r] = f2b(val.y);
        Qs[c4 * 4 + 2][r] = f2b(val.z);
        Qs[c4 * 4 + 3][r] = f2b(val.w);
    }
    if (tid < 64) { rowm[tid] = -1e30f; rowl[tid] = 0.f; }

    const int tm = tid & 15, tn = tid >> 4;
    const int tm4 = tm * 4, tn4 = tn * 4;
    const int zb = (tn - tm) * 4 + 60;   // multiple of 4, in [0,120]

    float accO[4][4] = {};

    for (int jt = 0; jt <= ix; ++jt) {
        const int t0 = jt * 64;
        const int jbase = S - 64 - s0 + t0;   // >= 0
        __syncthreads();   // prior PV done (and Q staging visible on iter 0)

        // Stage K (transposed) and V (natural)
        #pragma unroll
        for (int it = 0; it < 4; ++it) {
            int idx = tid + it * 256;
            int r = idx >> 4, c4 = idx & 15;
            float4 kv4 = *(const float4*)&kb[(size_t)(t0 + r) * Dh + c4 * 4];
            KsT[c4 * 4 + 0][r] = f2b(kv4.x);
            KsT[c4 * 4 + 1][r] = f2b(kv4.y);
            KsT[c4 * 4 + 2][r] = f2b(kv4.z);
            KsT[c4 * 4 + 3][r] = f2b(kv4.w);
            float4 vv4 = *(const float4*)&vb[(size_t)(t0 + r) * Dh + c4 * 4];
            ushort4 sv;
            sv.x = f2b(vv4.x); sv.y = f2b(vv4.y);
            sv.z = f2b(vv4.z); sv.w = f2b(vv4.w);
            *(ushort4*)&Vs[r][c4 * 4] = sv;
        }
        // Stage Er window rows jbase..jbase+127 (transposed to [d][z])
        #pragma unroll
        for (int it = 0; it < 8; ++it) {
            int idx = tid + it * 256;      // 0..2047
            int zz = idx >> 4, c4 = idx & 15;
            int jr = jbase + zz; if (jr > S - 1) jr = S - 1;  // clamp (masked anyway)
            float4 ev = *(const float4*)&Er[(size_t)jr * Dh + c4 * 4];
            Es[c4 * 4 + 0][zz] = f2b(ev.x);
            Es[c4 * 4 + 1][zz] = f2b(ev.y);
            Es[c4 * 4 + 2][zz] = f2b(ev.z);
            Es[c4 * 4 + 3][zz] = f2b(ev.w);
        }
        __syncthreads();

        // Scores: acc[i][j] = sum_d q[m]*(k[n] + er[z]),  z = n-m+63
        float acc[4][4] = {};
        #pragma unroll 4
        for (int d = 0; d < 64; ++d) {
            ushort4 qa = *(const ushort4*)&Qs[d][tm4];
            ushort4 ka = *(const ushort4*)&KsT[d][tn4];
            ushort4 e0 = *(const ushort4*)&Es[d][zb];
            ushort4 e1 = *(const ushort4*)&Es[d][zb + 4];
            float aq[4]  = { b2f(qa.x), b2f(qa.y), b2f(qa.z), b2f(qa.w) };
            float bk4[4] = { b2f(ka.x), b2f(ka.y), b2f(ka.z), b2f(ka.w) };
            float e8[8]  = { b2f(e0.x), b2f(e0.y), b2f(e0.z), b2f(e0.w),
                             b2f(e1.x), b2f(e1.y), b2f(e1.z), b2f(e1.w) };
            #pragma unroll
            for (int i = 0; i < 4; ++i)
                #pragma unroll
                for (int j = 0; j < 4; ++j)
                    acc[i][j] += aq[i] * (bk4[j] + e8[j - i + 3]);
        }

        // Scale, causal mask (diagonal tile only), store transposed to Sc[n][m]
        const bool diag = (jt == ix);
        #pragma unroll
        for (int i = 0; i < 4; ++i)
            #pragma unroll
            for (int j = 0; j < 4; ++j) {
                float sv = acc[i][j] * 0.125f;
                if (diag && (tn4 + j > tm4 + i)) sv = -1e30f;
                Sc[tn4 + j][tm4 + i] = sv;
            }
        __syncthreads();

        // Online softmax row update (one wave)
        if (tid < 64) {
            int m = tid;
            float mold = rowm[m];
            float tmax = -1e30f;
            for (int n = 0; n < 64; ++n) tmax = fmaxf(tmax, Sc[n][m]);
            float mnew = fmaxf(mold, tmax);
            float alpha = __expf(mold - mnew);
            float sum = 0.f;
            for (int n = 0; n < 64; ++n) {
                float p = __expf(Sc[n][m] - mnew);
                Sc[n][m] = p;
                sum += p;
            }
            rowl[m] = rowl[m] * alpha + sum;
            rowm[m] = mnew;
            rowA[m] = alpha;
        }
        __syncthreads();

        // Rescale O and accumulate P @ V
        float al[4];
        #pragma unroll
        for (int i = 0; i < 4; ++i) al[i] = rowA[tm4 + i];
        #pragma unroll
        for (int i = 0; i < 4; ++i)
            #pragma unroll
            for (int j = 0; j < 4; ++j) accO[i][j] *= al[i];
        for (int n = 0; n < 64; ++n) {
            float4 a4 = *(const float4*)&Sc[n][tm4];
            ushort4 vv = *(const ushort4*)&Vs[n][tn4];
            float pa[4] = { a4.x, a4.y, a4.z, a4.w };
            float vb4[4] = { b2f(vv.x), b2f(vv.y), b2f(vv.z), b2f(vv.w) };
            #pragma unroll
            for (int i = 0; i < 4; ++i)
                #pragma unroll
                for (int j = 0; j < 4; ++j)
                    accO[i][j] += pa[i] * vb4[j];
        }
    }

    // Epilogue: out[b, s, h*64+dh] = O / l
    float* ob = out + (size_t)bb * S * D + hh * 64;
    #pragma unroll
    for (int i = 0; i < 4; ++i) {
        int s = s0 + tm4 + i;
        float inv = 1.f / rowl[tm4 + i];
        float4 o;
        o.x = accO[i][0] * inv;
        o.y = accO[i][1] * inv;
        o.z = accO[i][2] * inv;
        o.w = accO[i][3] * inv;
        *(float4*)&ob[(size_t)s * D + tn4] = o;
    }
}

extern "C" void kernel_launch(void* const* d_in, const int* in_sizes, int n_in,
                              void* d_out, int out_size, void* d_ws, size_t ws_size,
                              hipStream_t stream) {
    const float* x  = (const float*)d_in[0];
    const float* Wq = (const float*)d_in[1];
    const float* bq = (const float*)d_in[2];
    const float* Wk = (const float*)d_in[3];
    const float* bk = (const float*)d_in[4];
    const float* Wv = (const float*)d_in[5];
    const float* bv = (const float*)d_in[6];
    const float* Er = (const float*)d_in[7];
    float* out = (float*)d_out;

    float* qw = (float*)d_ws;                     // B*H*S*Dh = 4194304 floats
    float* kw = qw + (size_t)B * H * S * Dh;
    float* vw = kw + (size_t)B * H * S * Dh;

    dim3 g1(64, 16, 3), b1(256);
    qkv_proj<<<g1, b1, 0, stream>>>(x, Wq, bq, Wk, bk, Wv, bv, qw, kw, vw);

    dim3 g2(S / 64, B * H), b2(256);
    attn_kernel<<<g2, b2, 0, stream>>>(qw, kw, vw, Er, out);
}

// Round 2
// 383.080 us; speedup vs baseline: 3.8776x; 3.8776x over previous
//
#include <hip/hip_runtime.h>
#include <hip/hip_bf16.h>

constexpr int B  = 2;
constexpr int S  = 2048;
constexpr int D  = 1024;
constexpr int H  = 16;

typedef unsigned short ushortT;
typedef unsigned long long u64;
typedef __attribute__((ext_vector_type(8))) short short8;
typedef __attribute__((ext_vector_type(4))) float float4v;

__device__ __forceinline__ float b2f(ushortT u) {
    union { unsigned int i; float f; } c; c.i = ((unsigned int)u) << 16; return c.f;
}
__device__ __forceinline__ ushortT f2b(float f) {
    __hip_bfloat16 h = __float2bfloat16(f);
    union { __hip_bfloat16 h; ushortT u; } c; c.h = h; return c.u;
}
__device__ __forceinline__ u64 pack4(float4 v) {
    return (u64)f2b(v.x) | ((u64)f2b(v.y) << 16) | ((u64)f2b(v.z) << 32) | ((u64)f2b(v.w) << 48);
}

// ---------------------------------------------------------------------------
// Er fp32 -> bf16 conversion (2048*64 = 131072 elements = 32768 float4)
// ---------------------------------------------------------------------------
__global__ __launch_bounds__(256) void er_to_bf16(const float* __restrict__ in,
                                                  ushortT* __restrict__ out) {
    int i = blockIdx.x * 256 + threadIdx.x;   // float4 index
    float4 v = ((const float4*)in)[i];
    ((u64*)out)[i] = pack4(v);
}

// ---------------------------------------------------------------------------
// QKV projection, bf16 MFMA.  C[m][n] = sum_k X[m][k]*W[n][k] + bias[n]
// BM=BN=128, BK=32.  4 waves, each a 64x64 quadrant (4x4 of 16x16 tiles).
// Output bf16 in (B,H,S,Dh) layout.
// ---------------------------------------------------------------------------
__global__ __launch_bounds__(256) void qkv_mfma(
    const float* __restrict__ x,
    const float* __restrict__ Wq, const float* __restrict__ bq,
    const float* __restrict__ Wk, const float* __restrict__ bk,
    const float* __restrict__ Wv, const float* __restrict__ bv,
    ushortT* __restrict__ qo, ushortT* __restrict__ ko, ushortT* __restrict__ vo)
{
    const int z = blockIdx.z;
    const float* W    = (z == 0) ? Wq : (z == 1) ? Wk : Wv;
    const float* bias = (z == 0) ? bq : (z == 1) ? bk : bv;
    ushortT*     out  = (z == 0) ? qo : (z == 1) ? ko : vo;

    __shared__ __align__(16) ushortT Xs[128][40];  // stride 80B: frag reads 2-way free
    __shared__ __align__(16) ushortT Ws[128][40];

    const int tid  = threadIdx.x;
    const int w    = tid >> 6, lane = tid & 63;
    const int quad = lane >> 4, l16 = lane & 15;
    const int m0 = blockIdx.x * 128, n0 = blockIdx.y * 128;
    const int mi = (w >> 1) * 64, ni = (w & 1) * 64;   // wave quadrant

    float4v acc[4][4];
    #pragma unroll
    for (int mt = 0; mt < 4; ++mt)
        #pragma unroll
        for (int nt = 0; nt < 4; ++nt) acc[mt][nt] = (float4v){0.f, 0.f, 0.f, 0.f};

    for (int k0 = 0; k0 < D; k0 += 32) {
        float4 xa[4], wa[4];
        #pragma unroll
        for (int it = 0; it < 4; ++it) {
            int idx = tid + it * 256, rr = idx >> 3, cc = idx & 7;
            xa[it] = *(const float4*)&x[(size_t)(m0 + rr) * D + k0 + cc * 4];
            wa[it] = *(const float4*)&W[(size_t)(n0 + rr) * D + k0 + cc * 4];
        }
        __syncthreads();
        #pragma unroll
        for (int it = 0; it < 4; ++it) {
            int idx = tid + it * 256, rr = idx >> 3, cc = idx & 7;
            *(u64*)&Xs[rr][cc * 4] = pack4(xa[it]);
            *(u64*)&Ws[rr][cc * 4] = pack4(wa[it]);
        }
        __syncthreads();
        short8 af[4], bf[4];
        #pragma unroll
        for (int mt = 0; mt < 4; ++mt)
            af[mt] = *(const short8*)&Xs[mi + mt * 16 + l16][quad * 8];
        #pragma unroll
        for (int nt = 0; nt < 4; ++nt)
            bf[nt] = *(const short8*)&Ws[ni + nt * 16 + l16][quad * 8];
        #pragma unroll
        for (int mt = 0; mt < 4; ++mt)
            #pragma unroll
            for (int nt = 0; nt < 4; ++nt)
                acc[mt][nt] = __builtin_amdgcn_mfma_f32_16x16x32_bf16(
                    af[mt], bf[nt], acc[mt][nt], 0, 0, 0);
    }

    float bias_v[4];
    #pragma unroll
    for (int nt = 0; nt < 4; ++nt) bias_v[nt] = bias[n0 + ni + nt * 16 + l16];

    #pragma unroll
    for (int mt = 0; mt < 4; ++mt)
        #pragma unroll
        for (int nt = 0; nt < 4; ++nt) {
            int n = n0 + ni + nt * 16 + l16;
            int h = n >> 6, dh = n & 63;
            #pragma unroll
            for (int rg = 0; rg < 4; ++rg) {
                int m  = m0 + mi + mt * 16 + quad * 4 + rg;
                int b_ = m >> 11, s = m & (S - 1);
                out[(((size_t)(b_ * H + h)) * S + s) * 64 + dh] =
                    f2b(acc[mt][nt][rg] + bias_v[nt]);
            }
        }
}

// ---------------------------------------------------------------------------
// Flash attention with relative-position term, bf16 MFMA.
// score(i,j) = ( q_i·k_j + q_i·Er[S-1-i+j] ) / 8, causal.
// One block = 4 waves = (bh, 64-row q tile). Q frags live in registers.
// Per jt: stage K+ErWin -> QK & QEr GEMMs -> stage V^T over K -> register
// softmax (shfl row-reduce) -> P to LDS -> PV GEMM.
// ---------------------------------------------------------------------------
__global__ __launch_bounds__(256) void attn_mfma(
    const ushortT* __restrict__ q, const ushortT* __restrict__ k,
    const ushortT* __restrict__ v, const ushortT* __restrict__ er,
    float* __restrict__ out)
{
    __shared__ __align__(16) ushortT KVs [64][72];   // K natural, then V^T
    __shared__ __align__(16) ushortT ErW [128][72];  // Er window, natural [z][d]
    __shared__ __align__(16) ushortT QErS[64][136];  // QEr result bf16 [i][z]
    __shared__ __align__(16) ushortT Ps  [64][72];   // probabilities bf16 [i][t]

    const int tid  = threadIdx.x;
    const int w    = tid >> 6, lane = tid & 63;
    const int quad = lane >> 4, l16 = lane & 15;
    const int ix = blockIdx.x, bh = blockIdx.y;
    const int s0 = ix * 64;
    const int hh = bh & (H - 1), bb = bh >> 4;

    const ushortT* qb = q + (size_t)bh * S * 64;
    const ushortT* kb = k + (size_t)bh * S * 64;
    const ushortT* vb = v + (size_t)bh * S * 64;

    // Q A-fragments: row (s0 + w*16 + l16), all 64 k, in registers forever.
    const size_t qoff = (size_t)(s0 + w * 16 + l16) * 64;
    short8 Qa0 = *(const short8*)&qb[qoff + quad * 8];
    short8 Qa1 = *(const short8*)&qb[qoff + 32 + quad * 8];

    float4v accO[4];
    #pragma unroll
    for (int t = 0; t < 4; ++t) accO[t] = (float4v){0.f, 0.f, 0.f, 0.f};
    float mrow[4] = {-1e30f, -1e30f, -1e30f, -1e30f};
    float lrow[4] = {0.f, 0.f, 0.f, 0.f};

    for (int jt = 0; jt <= ix; ++jt) {
        const int t0 = jt * 64;
        const int jbase = S - 64 - s0 + t0;     // >= 0
        __syncthreads();   // prior PV reads of KVs/Ps done

        // ---- stage K (natural) and Er window ----
        #pragma unroll
        for (int it = 0; it < 4; ++it) {
            int idx = tid + it * 256, r = idx >> 4, c4 = idx & 15;
            *(u64*)&KVs[r][c4 * 4] = *(const u64*)&kb[(size_t)(t0 + r) * 64 + c4 * 4];
        }
        #pragma unroll
        for (int it = 0; it < 8; ++it) {
            int idx = tid + it * 256, r = idx >> 4, c4 = idx & 15;
            int jr = jbase + r; jr = (jr > S - 1) ? (S - 1) : jr;  // clamped rows are masked
            *(u64*)&ErW[r][c4 * 4] = *(const u64*)&er[(size_t)jr * 64 + c4 * 4];
        }
        __syncthreads();

        // ---- QK^T : S1[nt] (16x16 C-layout), nt over 4 col-tiles ----
        float4v S1[4];
        #pragma unroll
        for (int nt = 0; nt < 4; ++nt) {
            float4v a = (float4v){0.f, 0.f, 0.f, 0.f};
            short8 b0 = *(const short8*)&KVs[nt * 16 + l16][quad * 8];
            short8 b1 = *(const short8*)&KVs[nt * 16 + l16][32 + quad * 8];
            a = __builtin_amdgcn_mfma_f32_16x16x32_bf16(Qa0, b0, a, 0, 0, 0);
            a = __builtin_amdgcn_mfma_f32_16x16x32_bf16(Qa1, b1, a, 0, 0, 0);
            S1[nt] = a;
        }
        // ---- QEr : 64x128 GEMM, result to LDS as bf16 ----
        #pragma unroll
        for (int nt = 0; nt < 8; ++nt) {
            float4v e = (float4v){0.f, 0.f, 0.f, 0.f};
            short8 b0 = *(const short8*)&ErW[nt * 16 + l16][quad * 8];
            short8 b1 = *(const short8*)&ErW[nt * 16 + l16][32 + quad * 8];
            e = __builtin_amdgcn_mfma_f32_16x16x32_bf16(Qa0, b0, e, 0, 0, 0);
            e = __builtin_amdgcn_mfma_f32_16x16x32_bf16(Qa1, b1, e, 0, 0, 0);
            #pragma unroll
            for (int rg = 0; rg < 4; ++rg)
                QErS[w * 16 + quad * 4 + rg][nt * 16 + l16] = f2b(e[rg]);
        }
        __syncthreads();   // QErS visible; all waves done reading K from KVs

        // ---- stage V^T into KVs (overwrites K) ----
        #pragma unroll
        for (int it = 0; it < 2; ++it) {
            int idx = tid + it * 256;
            int d4 = idx & 15, tp = idx >> 4;   // tp in [0,32): t-pair
            u64 v0 = *(const u64*)&vb[(size_t)(t0 + tp * 2)     * 64 + d4 * 4];
            u64 v1 = *(const u64*)&vb[(size_t)(t0 + tp * 2 + 1) * 64 + d4 * 4];
            #pragma unroll
            for (int dd = 0; dd < 4; ++dd) {
                unsigned int pr = ((unsigned int)(ushortT)(v0 >> (16 * dd))) |
                                  (((unsigned int)(ushortT)(v1 >> (16 * dd))) << 16);
                *(unsigned int*)&KVs[d4 * 4 + dd][tp * 2] = pr;
            }
        }

        // ---- scores + register softmax ----
        const bool diag = (jt == ix);
        float sv[4][4];
        #pragma unroll
        for (int nt = 0; nt < 4; ++nt) {
            int j = nt * 16 + l16;
            #pragma unroll
            for (int rg = 0; rg < 4; ++rg) {
                int i = w * 16 + quad * 4 + rg;
                float qe = b2f(QErS[i][j - i + 63]);
                float s = (S1[nt][rg] + qe) * 0.125f;
                if (diag && (j > i)) s = -1e30f;
                sv[nt][rg] = s;
            }
        }
        #pragma unroll
        for (int rg = 0; rg < 4; ++rg) {
            float mx = fmaxf(fmaxf(sv[0][rg], sv[1][rg]), fmaxf(sv[2][rg], sv[3][rg]));
            mx = fmaxf(mx, __shfl_xor(mx, 1));
            mx = fmaxf(mx, __shfl_xor(mx, 2));
            mx = fmaxf(mx, __shfl_xor(mx, 4));
            mx = fmaxf(mx, __shfl_xor(mx, 8));
            float mnew  = fmaxf(mrow[rg], mx);
            float alpha = __expf(mrow[rg] - mnew);
            mrow[rg] = mnew;
            float sum = 0.f;
            #pragma unroll
            for (int nt = 0; nt < 4; ++nt) {
                float p = __expf(sv[nt][rg] - mnew);
                sum += p;
                Ps[w * 16 + quad * 4 + rg][nt * 16 + l16] = f2b(p);
            }
            sum += __shfl_xor(sum, 1);
            sum += __shfl_xor(sum, 2);
            sum += __shfl_xor(sum, 4);
            sum += __shfl_xor(sum, 8);
            lrow[rg] = lrow[rg] * alpha + sum;
            #pragma unroll
            for (int td = 0; td < 4; ++td) accO[td][rg] *= alpha;
        }
        __syncthreads();   // Ps + V^T visible

        // ---- PV : O += P @ V ----
        short8 pa0 = *(const short8*)&Ps[w * 16 + l16][quad * 8];
        short8 pa1 = *(const short8*)&Ps[w * 16 + l16][32 + quad * 8];
        #pragma unroll
        for (int td = 0; td < 4; ++td) {
            short8 b0 = *(const short8*)&KVs[td * 16 + l16][quad * 8];
            short8 b1 = *(const short8*)&KVs[td * 16 + l16][32 + quad * 8];
            accO[td] = __builtin_amdgcn_mfma_f32_16x16x32_bf16(pa0, b0, accO[td], 0, 0, 0);
            accO[td] = __builtin_amdgcn_mfma_f32_16x16x32_bf16(pa1, b1, accO[td], 0, 0, 0);
        }
    }

    // ---- epilogue: out[b, s, h*64 + d] = O / l ----
    float* ob = out + (size_t)bb * S * D + (size_t)hh * 64;
    #pragma unroll
    for (int rg = 0; rg < 4; ++rg) {
        int s = s0 + w * 16 + quad * 4 + rg;
        float inv = 1.f / lrow[rg];
        #pragma unroll
        for (int td = 0; td < 4; ++td)
            ob[(size_t)s * D + td * 16 + l16] = accO[td][rg] * inv;
    }
}

extern "C" void kernel_launch(void* const* d_in, const int* in_sizes, int n_in,
                              void* d_out, int out_size, void* d_ws, size_t ws_size,
                              hipStream_t stream) {
    const float* x  = (const float*)d_in[0];
    const float* Wq = (const float*)d_in[1];
    const float* bq = (const float*)d_in[2];
    const float* Wk = (const float*)d_in[3];
    const float* bk = (const float*)d_in[4];
    const float* Wv = (const float*)d_in[5];
    const float* bv = (const float*)d_in[6];
    const float* Er = (const float*)d_in[7];
    float* out = (float*)d_out;

    const size_t NQ = (size_t)B * H * S * 64;   // 4194304
    ushortT* qw = (ushortT*)d_ws;
    ushortT* kw = qw + NQ;
    ushortT* vw = kw + NQ;
    ushortT* ew = vw + NQ;                      // 2048*64 bf16

    er_to_bf16<<<dim3(S * 64 / 1024), dim3(256), 0, stream>>>(Er, ew);

    dim3 g1(32, 8, 3), b1(256);
    qkv_mfma<<<g1, b1, 0, stream>>>(x, Wq, bq, Wk, bk, Wv, bv, qw, kw, vw);

    dim3 g2(S / 64, B * H), b2(256);
    attn_mfma<<<g2, b2, 0, stream>>>(qw, kw, vw, ew, out);
}